// Round 3
// baseline (909.145 us; speedup 1.0000x reference)
//
#include <hip/hip_runtime.h>

#define HID 128
#define EPSF 1e-6f

// ---------------- histogram of x (65 bins) ----------------
__global__ void k_hist(const int* __restrict__ x, int n, int* __restrict__ hist) {
  __shared__ int lh[65];
  int t = threadIdx.x;
  if (t < 65) lh[t] = 0;
  __syncthreads();
  for (int i = blockIdx.x * blockDim.x + t; i < n; i += gridDim.x * blockDim.x)
    atomicAdd(&lh[x[i]], 1);
  __syncthreads();
  if (t < 65 && lh[t]) atomicAdd(&hist[t], lh[t]);
}

// ---------------- deg (weighted) + per-row edge count ----------------
__global__ void k_degcnt(const int* __restrict__ row, const float* __restrict__ ew, int e,
                         float* __restrict__ deg, int* __restrict__ cnt) {
  for (int i = blockIdx.x * blockDim.x + threadIdx.x; i < e; i += gridDim.x * blockDim.x) {
    int r = row[i];
    atomicAdd(&deg[r], ew[i]);
    atomicAdd(&cnt[r], 1);
  }
}

// ---------------- 3-phase exclusive scan over cnt[0..n) -> rowptr ----------------
__global__ void k_scan_partial(const int* __restrict__ cnt, int n, int* __restrict__ bsum) {
  __shared__ int sh[256];
  int t = threadIdx.x;
  int base = blockIdx.x * 2048 + t * 8;
  int s = 0;
#pragma unroll
  for (int j = 0; j < 8; ++j) { int idx = base + j; if (idx < n) s += cnt[idx]; }
  sh[t] = s; __syncthreads();
  for (int off = 128; off > 0; off >>= 1) {
    if (t < off) sh[t] += sh[t + off];
    __syncthreads();
  }
  if (t == 0) bsum[blockIdx.x] = sh[0];
}

__global__ void k_scan_bsum(int* __restrict__ bsum, int nb) {
  if (threadIdx.x == 0 && blockIdx.x == 0) {
    int acc = 0;
    for (int i = 0; i < nb; ++i) { int v = bsum[i]; bsum[i] = acc; acc += v; }
  }
}

__global__ void k_scan_final(const int* __restrict__ cnt, int n, const int* __restrict__ bsum,
                             int* __restrict__ rowptr, int* __restrict__ cursor) {
  __shared__ int sh[256];
  int t = threadIdx.x;
  int base = blockIdx.x * 2048 + t * 8;
  int v[8]; int s = 0;
#pragma unroll
  for (int j = 0; j < 8; ++j) { int idx = base + j; v[j] = (idx < n) ? cnt[idx] : 0; s += v[j]; }
  sh[t] = s; __syncthreads();
  for (int off = 1; off < 256; off <<= 1) {
    int val = (t >= off) ? sh[t - off] : 0;
    __syncthreads();
    sh[t] += val;
    __syncthreads();
  }
  int off0 = bsum[blockIdx.x] + sh[t] - s;  // exclusive prefix for this thread
#pragma unroll
  for (int j = 0; j < 8; ++j) {
    int idx = base + j;
    if (idx < n) { rowptr[idx] = off0; cursor[idx] = off0; off0 += v[j]; }
  }
}

// ---------------- scatter edges into CSR order, fusing w_norm ----------------
__global__ void k_scatter(const int* __restrict__ row, const int* __restrict__ col,
                          const float* __restrict__ ew, int e,
                          const float* __restrict__ deg, int* __restrict__ cursor,
                          int2* __restrict__ sedge) {
  for (int i = blockIdx.x * blockDim.x + threadIdx.x; i < e; i += gridDim.x * blockDim.x) {
    int r = row[i];
    float d = deg[r];
    d = (d < 0.5f) ? d + 1.0f : d;
    float wn = ew[i] / d;
    int pos = atomicAdd(&cursor[r], 1);
    sedge[pos] = make_int2(col[i], __float_as_int(wn));
  }
}

// ---------------- fold GN0 into the embedding table ----------------
__global__ void k_gn0(const float* __restrict__ emb, const int* __restrict__ hist,
                      const float* __restrict__ gw, const float* __restrict__ gb,
                      const float* __restrict__ gms, float invN,
                      float* __restrict__ emb1) {
  int d = threadIdx.x;  // 128 threads
  float s = 0.f, s2 = 0.f;
  for (int k = 0; k < 65; ++k) {
    float v = emb[k * HID + d];
    float c = (float)hist[k];
    s += c * v; s2 += c * v * v;
  }
  float m = s * invN, E2 = s2 * invN;
  float ms0 = gms[d], w0 = gw[d], b0 = gb[d];
  float sh = m * ms0;
  float a = w0 / sqrtf(E2 - 2.f * sh * m + sh * sh + EPSF);
  float c = b0 - a * sh;
  for (int k = 0; k < 65; ++k) emb1[k * HID + d] = fmaf(a, emb[k * HID + d], c);
}

// ---------------- chained double-GraphNorm -> per-column affine ----------------
__global__ void k_gnchain(const float* __restrict__ gsum, const float* __restrict__ gsq,
                          float invN, const float* __restrict__ gw, const float* __restrict__ gb,
                          const float* __restrict__ gms, int i1, int i2,
                          float* __restrict__ A, float* __restrict__ C) {
  int d = threadIdx.x;  // 128 threads
  float m = gsum[d] * invN, E2 = gsq[d] * invN;
  float ms1 = gms[i1 * HID + d], w1 = gw[i1 * HID + d], b1 = gb[i1 * HID + d];
  float sh1 = m * ms1;
  float a1 = w1 / sqrtf(E2 - 2.f * sh1 * m + sh1 * sh1 + EPSF);
  float c1 = b1 - a1 * sh1;
  float m2 = a1 * m + c1;
  float E2b = a1 * a1 * E2 + 2.f * a1 * c1 * m + c1 * c1;
  float ms2 = gms[i2 * HID + d], w2 = gw[i2 * HID + d], b2 = gb[i2 * HID + d];
  float sh2 = m2 * ms2;
  float a2 = w2 / sqrtf(E2b - 2.f * sh2 * m2 + sh2 * sh2 + EPSF);
  float c2 = b2 - a2 * sh2;
  A[d] = a2 * a1;
  C[d] = a2 * c1 + c2;
}

// ---------------- SpMM1: gather from LDS-resident emb1 via x[col] ----------------
__global__ __launch_bounds__(256) void k_spmm1(
    const int* __restrict__ rowptr, const int2* __restrict__ sedge,
    const int* __restrict__ x, const float* __restrict__ emb1, int n,
    float* __restrict__ h2, float* __restrict__ gsum, float* __restrict__ gsq) {
  __shared__ float lemb[65 * HID];
  __shared__ float red[2][8][32][4];
  int t = threadIdx.x;
  for (int i = t; i < 65 * HID; i += 256) lemb[i] = emb1[i];
  __syncthreads();
  int l = t & 31, g = t >> 5;
  float ps0 = 0, ps1 = 0, ps2 = 0, ps3 = 0, q0 = 0, q1 = 0, q2 = 0, q3 = 0;
  for (int node = blockIdx.x * 8 + g; node < n; node += gridDim.x * 8) {
    int p0 = rowptr[node], p1 = rowptr[node + 1];
    float a0 = 0, a1 = 0, a2 = 0, a3 = 0;
    for (int p = p0; p < p1; ++p) {
      int2 cw = sedge[p];
      float wn = __int_as_float(cw.y);
      int xc = x[cw.x];
      const float4 v = *(const float4*)&lemb[xc * HID + l * 4];
      a0 += wn * v.x; a1 += wn * v.y; a2 += wn * v.z; a3 += wn * v.w;
    }
    float4 st = {a0, a1, a2, a3};
    *(float4*)&h2[(size_t)node * HID + l * 4] = st;
    ps0 += a0; ps1 += a1; ps2 += a2; ps3 += a3;
    q0 += a0 * a0; q1 += a1 * a1; q2 += a2 * a2; q3 += a3 * a3;
  }
  red[0][g][l][0] = ps0; red[0][g][l][1] = ps1; red[0][g][l][2] = ps2; red[0][g][l][3] = ps3;
  red[1][g][l][0] = q0;  red[1][g][l][1] = q1;  red[1][g][l][2] = q2;  red[1][g][l][3] = q3;
  __syncthreads();
  if (g == 0) {
#pragma unroll
    for (int j = 0; j < 4; ++j) {
      float s = 0, s2 = 0;
#pragma unroll
      for (int gg = 0; gg < 8; ++gg) { s += red[0][gg][l][j]; s2 += red[1][gg][l][j]; }
      atomicAdd(&gsum[l * 4 + j], s);
      atomicAdd(&gsq[l * 4 + j], s2);
    }
  }
}

// ---------------- SpMM2: gather relu(A*h2+C) from global h2 ----------------
__global__ __launch_bounds__(256) void k_spmm2(
    const int* __restrict__ rowptr, const int2* __restrict__ sedge,
    const float* __restrict__ h2, const float* __restrict__ A, const float* __restrict__ C,
    int n, float* __restrict__ out, float* __restrict__ gsum, float* __restrict__ gsq) {
  __shared__ float red[2][8][32][4];
  int t = threadIdx.x;
  int l = t & 31, g = t >> 5;
  float Aa0 = A[l * 4 + 0], Aa1 = A[l * 4 + 1], Aa2 = A[l * 4 + 2], Aa3 = A[l * 4 + 3];
  float Cc0 = C[l * 4 + 0], Cc1 = C[l * 4 + 1], Cc2 = C[l * 4 + 2], Cc3 = C[l * 4 + 3];
  float ps0 = 0, ps1 = 0, ps2 = 0, ps3 = 0, q0 = 0, q1 = 0, q2 = 0, q3 = 0;
  for (int node = blockIdx.x * 8 + g; node < n; node += gridDim.x * 8) {
    int p0 = rowptr[node], p1 = rowptr[node + 1];
    float a0 = 0, a1 = 0, a2 = 0, a3 = 0;
    for (int p = p0; p < p1; ++p) {
      int2 cw = sedge[p];
      float wn = __int_as_float(cw.y);
      const float4 v = *(const float4*)&h2[(size_t)cw.x * HID + l * 4];
      float y0 = fmaxf(fmaf(Aa0, v.x, Cc0), 0.f);
      float y1 = fmaxf(fmaf(Aa1, v.y, Cc1), 0.f);
      float y2 = fmaxf(fmaf(Aa2, v.z, Cc2), 0.f);
      float y3 = fmaxf(fmaf(Aa3, v.w, Cc3), 0.f);
      a0 += wn * y0; a1 += wn * y1; a2 += wn * y2; a3 += wn * y3;
    }
    float4 st = {a0, a1, a2, a3};
    *(float4*)&out[(size_t)node * HID + l * 4] = st;
    ps0 += a0; ps1 += a1; ps2 += a2; ps3 += a3;
    q0 += a0 * a0; q1 += a1 * a1; q2 += a2 * a2; q3 += a3 * a3;
  }
  red[0][g][l][0] = ps0; red[0][g][l][1] = ps1; red[0][g][l][2] = ps2; red[0][g][l][3] = ps3;
  red[1][g][l][0] = q0;  red[1][g][l][1] = q1;  red[1][g][l][2] = q2;  red[1][g][l][3] = q3;
  __syncthreads();
  if (g == 0) {
#pragma unroll
    for (int j = 0; j < 4; ++j) {
      float s = 0, s2 = 0;
#pragma unroll
      for (int gg = 0; gg < 8; ++gg) { s += red[0][gg][l][j]; s2 += red[1][gg][l][j]; }
      atomicAdd(&gsum[l * 4 + j], s);
      atomicAdd(&gsq[l * 4 + j], s2);
    }
  }
}

// ---------------- final in-place affine on d_out ----------------
__global__ void k_final(float* __restrict__ out, const float* __restrict__ A,
                        const float* __restrict__ C, int n) {
  __shared__ float la[HID], lc[HID];
  if (threadIdx.x < HID) { la[threadIdx.x] = A[threadIdx.x]; lc[threadIdx.x] = C[threadIdx.x]; }
  __syncthreads();
  int total = n * 32;  // float4 count
  for (int i = blockIdx.x * blockDim.x + threadIdx.x; i < total; i += gridDim.x * blockDim.x) {
    float4 v = *(float4*)(out + (size_t)i * 4);
    int cg = (i & 31) * 4;
    v.x = fmaf(la[cg + 0], v.x, lc[cg + 0]);
    v.y = fmaf(la[cg + 1], v.y, lc[cg + 1]);
    v.z = fmaf(la[cg + 2], v.z, lc[cg + 2]);
    v.w = fmaf(la[cg + 3], v.w, lc[cg + 3]);
    *(float4*)(out + (size_t)i * 4) = v;
  }
}

extern "C" void kernel_launch(void* const* d_in, const int* in_sizes, int n_in,
                              void* d_out, int out_size, void* d_ws, size_t ws_size,
                              hipStream_t stream) {
  const int* x = (const int*)d_in[0];
  const int* ei = (const int*)d_in[1];
  const float* ew = (const float*)d_in[2];
  const float* emb = (const float*)d_in[3];
  const float* gw = (const float*)d_in[4];
  const float* gb = (const float*)d_in[5];
  const float* gms = (const float*)d_in[6];
  float* out = (float*)d_out;

  const int n = in_sizes[0];        // 100000
  const int e = in_sizes[1] / 2;    // 1600000
  const int* row = ei;
  const int* col = ei + e;

  // workspace layout, in 4-byte units, 128B-aligned chunks
  float* wsf = (float*)d_ws;
  size_t o = 0;
  auto alloc = [&](size_t elems) -> size_t { size_t r = o; o += ((elems + 31) & ~(size_t)31); return r; };
  size_t deg_o = alloc(n);
  size_t cnt_o = alloc(n + 1);
  size_t hist_o = alloc(65);
  size_t sum2_o = alloc(HID), sq2_o = alloc(HID), sum4_o = alloc(HID), sq4_o = alloc(HID);
  size_t zero_end = o;                       // everything above must be zeroed
  size_t A12_o = alloc(HID), C12_o = alloc(HID), A34_o = alloc(HID), C34_o = alloc(HID);
  size_t rowptr_o = alloc(n + 1);
  size_t cursor_o = alloc(n + 1);
  size_t bsum_o = alloc(64);
  size_t emb1_o = alloc(65 * HID);
  size_t sedge_o = alloc((size_t)e * 2);     // int2 per edge
  size_t h2_o = alloc((size_t)n * HID);

  float* deg = wsf + deg_o;
  int* cnt = (int*)(wsf + cnt_o);
  int* hist = (int*)(wsf + hist_o);
  float* sum2 = wsf + sum2_o; float* sq2 = wsf + sq2_o;
  float* sum4 = wsf + sum4_o; float* sq4 = wsf + sq4_o;
  float* A12 = wsf + A12_o; float* C12 = wsf + C12_o;
  float* A34 = wsf + A34_o; float* C34 = wsf + C34_o;
  int* rowptr = (int*)(wsf + rowptr_o);
  int* cursor = (int*)(wsf + cursor_o);
  int* bsum = (int*)(wsf + bsum_o);
  float* emb1 = wsf + emb1_o;
  int2* sedge = (int2*)(wsf + sedge_o);
  float* h2 = wsf + h2_o;

  const float invN = 1.0f / (float)n;

  hipMemsetAsync(d_ws, 0, zero_end * sizeof(float), stream);
  k_hist<<<256, 256, 0, stream>>>(x, n, hist);
  k_degcnt<<<2048, 256, 0, stream>>>(row, ew, e, deg, cnt);
  int nb = (n + 1 + 2047) / 2048;
  k_scan_partial<<<nb, 256, 0, stream>>>(cnt, n + 1, bsum);
  k_scan_bsum<<<1, 64, 0, stream>>>(bsum, nb);
  k_scan_final<<<nb, 256, 0, stream>>>(cnt, n + 1, bsum, rowptr, cursor);
  k_scatter<<<2048, 256, 0, stream>>>(row, col, ew, e, deg, cursor, sedge);
  k_gn0<<<1, HID, 0, stream>>>(emb, hist, gw, gb, gms, invN, emb1);
  k_spmm1<<<2048, 256, 0, stream>>>(rowptr, sedge, x, emb1, n, h2, sum2, sq2);
  k_gnchain<<<1, HID, 0, stream>>>(sum2, sq2, invN, gw, gb, gms, 1, 2, A12, C12);
  k_spmm2<<<2048, 256, 0, stream>>>(rowptr, sedge, h2, A12, C12, n, out, sum4, sq4);
  k_gnchain<<<1, HID, 0, stream>>>(sum4, sq4, invN, gw, gb, gms, 3, 4, A34, C34);
  k_final<<<2048, 256, 0, stream>>>(out, A34, C34, n);
}

// Round 4
// 841.206 us; speedup vs baseline: 1.0808x; 1.0808x over previous
//
#include <hip/hip_runtime.h>

#define HID 128
#define EPSF 1e-6f

__device__ inline unsigned short f2bf(float f) {
  unsigned u = __float_as_uint(f);
  unsigned r = (u + 0x7fffu + ((u >> 16) & 1u)) >> 16;  // RNE
  return (unsigned short)r;
}
__device__ inline float bf2f(unsigned short h) {
  return __uint_as_float((unsigned)h << 16);
}

// ---------------- histogram of x (65 bins) ----------------
__global__ void k_hist(const int* __restrict__ x, int n, int* __restrict__ hist) {
  __shared__ int lh[65];
  int t = threadIdx.x;
  if (t < 65) lh[t] = 0;
  __syncthreads();
  for (int i = blockIdx.x * blockDim.x + t; i < n; i += gridDim.x * blockDim.x)
    atomicAdd(&lh[x[i]], 1);
  __syncthreads();
  if (t < 65 && lh[t]) atomicAdd(&hist[t], lh[t]);
}

// ---------------- deg (weighted) + per-row edge count ----------------
__global__ void k_degcnt(const int* __restrict__ row, const float* __restrict__ ew, int e,
                         float* __restrict__ deg, int* __restrict__ cnt) {
  for (int i = blockIdx.x * blockDim.x + threadIdx.x; i < e; i += gridDim.x * blockDim.x) {
    int r = row[i];
    atomicAdd(&deg[r], ew[i]);
    atomicAdd(&cnt[r], 1);
  }
}

// ---------------- 3-phase exclusive scan over cnt[0..n) -> rowptr ----------------
__global__ void k_scan_partial(const int* __restrict__ cnt, int n, int* __restrict__ bsum) {
  __shared__ int sh[256];
  int t = threadIdx.x;
  int base = blockIdx.x * 2048 + t * 8;
  int s = 0;
#pragma unroll
  for (int j = 0; j < 8; ++j) { int idx = base + j; if (idx < n) s += cnt[idx]; }
  sh[t] = s; __syncthreads();
  for (int off = 128; off > 0; off >>= 1) {
    if (t < off) sh[t] += sh[t + off];
    __syncthreads();
  }
  if (t == 0) bsum[blockIdx.x] = sh[0];
}

__global__ void k_scan_bsum(int* __restrict__ bsum, int nb) {
  if (threadIdx.x == 0 && blockIdx.x == 0) {
    int acc = 0;
    for (int i = 0; i < nb; ++i) { int v = bsum[i]; bsum[i] = acc; acc += v; }
  }
}

__global__ void k_scan_final(const int* __restrict__ cnt, int n, const int* __restrict__ bsum,
                             int* __restrict__ rowptr, int* __restrict__ cursor) {
  __shared__ int sh[256];
  int t = threadIdx.x;
  int base = blockIdx.x * 2048 + t * 8;
  int v[8]; int s = 0;
#pragma unroll
  for (int j = 0; j < 8; ++j) { int idx = base + j; v[j] = (idx < n) ? cnt[idx] : 0; s += v[j]; }
  sh[t] = s; __syncthreads();
  for (int off = 1; off < 256; off <<= 1) {
    int val = (t >= off) ? sh[t - off] : 0;
    __syncthreads();
    sh[t] += val;
    __syncthreads();
  }
  int off0 = bsum[blockIdx.x] + sh[t] - s;  // exclusive prefix for this thread
#pragma unroll
  for (int j = 0; j < 8; ++j) {
    int idx = base + j;
    if (idx < n) { rowptr[idx] = off0; cursor[idx] = off0; off0 += v[j]; }
  }
}

// ---------------- scatter edges into CSR order: (col, x[col], ew) ----------------
__global__ void k_scatter(const int* __restrict__ row, const int* __restrict__ col,
                          const float* __restrict__ ew, const int* __restrict__ x, int e,
                          int* __restrict__ cursor, int4* __restrict__ sedge) {
  for (int i = blockIdx.x * blockDim.x + threadIdx.x; i < e; i += gridDim.x * blockDim.x) {
    int r = row[i];
    int c = col[i];
    int xc = x[c];
    int pos = atomicAdd(&cursor[r], 1);
    sedge[pos] = make_int4(c, xc, __float_as_int(ew[i]), 0);
  }
}

// ---------------- fold GN0 into the embedding table ----------------
__global__ void k_gn0(const float* __restrict__ emb, const int* __restrict__ hist,
                      const float* __restrict__ gw, const float* __restrict__ gb,
                      const float* __restrict__ gms, float invN,
                      float* __restrict__ emb1) {
  int d = threadIdx.x;  // 128 threads
  float s = 0.f, s2 = 0.f;
  for (int k = 0; k < 65; ++k) {
    float v = emb[k * HID + d];
    float c = (float)hist[k];
    s += c * v; s2 += c * v * v;
  }
  float m = s * invN, E2 = s2 * invN;
  float ms0 = gms[d], w0 = gw[d], b0 = gb[d];
  float sh = m * ms0;
  float a = w0 / sqrtf(E2 - 2.f * sh * m + sh * sh + EPSF);
  float c = b0 - a * sh;
  for (int k = 0; k < 65; ++k) emb1[k * HID + d] = fmaf(a, emb[k * HID + d], c);
}

// ---------------- chained double-GraphNorm -> per-column affine ----------------
__global__ void k_gnchain(const float* __restrict__ gsum, const float* __restrict__ gsq,
                          float invN, const float* __restrict__ gw, const float* __restrict__ gb,
                          const float* __restrict__ gms, int i1, int i2,
                          float* __restrict__ A, float* __restrict__ C) {
  int d = threadIdx.x;  // 128 threads
  float m = gsum[d] * invN, E2 = gsq[d] * invN;
  float ms1 = gms[i1 * HID + d], w1 = gw[i1 * HID + d], b1 = gb[i1 * HID + d];
  float sh1 = m * ms1;
  float a1 = w1 / sqrtf(E2 - 2.f * sh1 * m + sh1 * sh1 + EPSF);
  float c1 = b1 - a1 * sh1;
  float m2 = a1 * m + c1;
  float E2b = a1 * a1 * E2 + 2.f * a1 * c1 * m + c1 * c1;
  float ms2 = gms[i2 * HID + d], w2 = gw[i2 * HID + d], b2 = gb[i2 * HID + d];
  float sh2 = m2 * ms2;
  float a2 = w2 / sqrtf(E2b - 2.f * sh2 * m2 + sh2 * sh2 + EPSF);
  float c2 = b2 - a2 * sh2;
  A[d] = a2 * a1;
  C[d] = a2 * c1 + c2;
}

// ---------------- SpMM1: LDS-resident emb1 gather via precomputed x[col] ----------------
__global__ __launch_bounds__(256) void k_spmm1(
    const int* __restrict__ rowptr, const int4* __restrict__ sedge,
    const float* __restrict__ emb1, const float* __restrict__ deg, int n,
    unsigned short* __restrict__ h2b, float* __restrict__ gsum, float* __restrict__ gsq) {
  __shared__ float lemb[65 * HID];
  __shared__ float red[2][8][32][4];
  int t = threadIdx.x;
  for (int i = t; i < 65 * HID; i += 256) lemb[i] = emb1[i];
  __syncthreads();
  int l = t & 31, g = t >> 5;
  float ps0 = 0, ps1 = 0, ps2 = 0, ps3 = 0, q0 = 0, q1 = 0, q2 = 0, q3 = 0;
  for (int node = blockIdx.x * 8 + g; node < n; node += gridDim.x * 8) {
    int p0 = rowptr[node], p1 = rowptr[node + 1];
    float d = deg[node];
    d = (d < 0.5f) ? d + 1.0f : d;
    float invd = 1.0f / d;
    float a0 = 0, a1 = 0, a2 = 0, a3 = 0;
    int p = p0;
    for (; p + 4 <= p1; p += 4) {
      int4 e0 = sedge[p], e1 = sedge[p + 1], e2 = sedge[p + 2], e3 = sedge[p + 3];
      const float4 v0 = *(const float4*)&lemb[e0.y * HID + l * 4];
      const float4 v1 = *(const float4*)&lemb[e1.y * HID + l * 4];
      const float4 v2 = *(const float4*)&lemb[e2.y * HID + l * 4];
      const float4 v3 = *(const float4*)&lemb[e3.y * HID + l * 4];
      float w0 = __int_as_float(e0.z), w1 = __int_as_float(e1.z);
      float w2 = __int_as_float(e2.z), w3 = __int_as_float(e3.z);
      a0 = fmaf(w0, v0.x, a0); a1 = fmaf(w0, v0.y, a1); a2 = fmaf(w0, v0.z, a2); a3 = fmaf(w0, v0.w, a3);
      a0 = fmaf(w1, v1.x, a0); a1 = fmaf(w1, v1.y, a1); a2 = fmaf(w1, v1.z, a2); a3 = fmaf(w1, v1.w, a3);
      a0 = fmaf(w2, v2.x, a0); a1 = fmaf(w2, v2.y, a1); a2 = fmaf(w2, v2.z, a2); a3 = fmaf(w2, v2.w, a3);
      a0 = fmaf(w3, v3.x, a0); a1 = fmaf(w3, v3.y, a1); a2 = fmaf(w3, v3.z, a2); a3 = fmaf(w3, v3.w, a3);
    }
    for (; p < p1; ++p) {
      int4 e0 = sedge[p];
      const float4 v0 = *(const float4*)&lemb[e0.y * HID + l * 4];
      float w0 = __int_as_float(e0.z);
      a0 = fmaf(w0, v0.x, a0); a1 = fmaf(w0, v0.y, a1); a2 = fmaf(w0, v0.z, a2); a3 = fmaf(w0, v0.w, a3);
    }
    a0 *= invd; a1 *= invd; a2 *= invd; a3 *= invd;
    ushort4 st;
    st.x = f2bf(a0); st.y = f2bf(a1); st.z = f2bf(a2); st.w = f2bf(a3);
    *(ushort4*)&h2b[(size_t)node * HID + l * 4] = st;
    ps0 += a0; ps1 += a1; ps2 += a2; ps3 += a3;
    q0 += a0 * a0; q1 += a1 * a1; q2 += a2 * a2; q3 += a3 * a3;
  }
  red[0][g][l][0] = ps0; red[0][g][l][1] = ps1; red[0][g][l][2] = ps2; red[0][g][l][3] = ps3;
  red[1][g][l][0] = q0;  red[1][g][l][1] = q1;  red[1][g][l][2] = q2;  red[1][g][l][3] = q3;
  __syncthreads();
  if (g == 0) {
#pragma unroll
    for (int j = 0; j < 4; ++j) {
      float s = 0, s2 = 0;
#pragma unroll
      for (int gg = 0; gg < 8; ++gg) { s += red[0][gg][l][j]; s2 += red[1][gg][l][j]; }
      atomicAdd(&gsum[l * 4 + j], s);
      atomicAdd(&gsq[l * 4 + j], s2);
    }
  }
}

// ---------------- SpMM2: gather relu(A*bf16(h2)+C) with 4-deep MLP ----------------
__global__ __launch_bounds__(256) void k_spmm2(
    const int* __restrict__ rowptr, const int4* __restrict__ sedge,
    const unsigned short* __restrict__ h2b, const float* __restrict__ deg,
    const float* __restrict__ A, const float* __restrict__ C,
    int n, float* __restrict__ out, float* __restrict__ gsum, float* __restrict__ gsq) {
  __shared__ float red[2][8][32][4];
  int t = threadIdx.x;
  int l = t & 31, g = t >> 5;
  float Aa0 = A[l * 4 + 0], Aa1 = A[l * 4 + 1], Aa2 = A[l * 4 + 2], Aa3 = A[l * 4 + 3];
  float Cc0 = C[l * 4 + 0], Cc1 = C[l * 4 + 1], Cc2 = C[l * 4 + 2], Cc3 = C[l * 4 + 3];
  float ps0 = 0, ps1 = 0, ps2 = 0, ps3 = 0, q0 = 0, q1 = 0, q2 = 0, q3 = 0;
  for (int node = blockIdx.x * 8 + g; node < n; node += gridDim.x * 8) {
    int p0 = rowptr[node], p1 = rowptr[node + 1];
    float d = deg[node];
    d = (d < 0.5f) ? d + 1.0f : d;
    float invd = 1.0f / d;
    float a0 = 0, a1 = 0, a2 = 0, a3 = 0;
    int p = p0;
    for (; p + 4 <= p1; p += 4) {
      int4 e0 = sedge[p], e1 = sedge[p + 1], e2 = sedge[p + 2], e3 = sedge[p + 3];
      ushort4 u0 = *(const ushort4*)&h2b[(size_t)e0.x * HID + l * 4];
      ushort4 u1 = *(const ushort4*)&h2b[(size_t)e1.x * HID + l * 4];
      ushort4 u2 = *(const ushort4*)&h2b[(size_t)e2.x * HID + l * 4];
      ushort4 u3 = *(const ushort4*)&h2b[(size_t)e3.x * HID + l * 4];
      float w0 = __int_as_float(e0.z), w1 = __int_as_float(e1.z);
      float w2 = __int_as_float(e2.z), w3 = __int_as_float(e3.z);
      a0 = fmaf(w0, fmaxf(fmaf(Aa0, bf2f(u0.x), Cc0), 0.f), a0);
      a1 = fmaf(w0, fmaxf(fmaf(Aa1, bf2f(u0.y), Cc1), 0.f), a1);
      a2 = fmaf(w0, fmaxf(fmaf(Aa2, bf2f(u0.z), Cc2), 0.f), a2);
      a3 = fmaf(w0, fmaxf(fmaf(Aa3, bf2f(u0.w), Cc3), 0.f), a3);
      a0 = fmaf(w1, fmaxf(fmaf(Aa0, bf2f(u1.x), Cc0), 0.f), a0);
      a1 = fmaf(w1, fmaxf(fmaf(Aa1, bf2f(u1.y), Cc1), 0.f), a1);
      a2 = fmaf(w1, fmaxf(fmaf(Aa2, bf2f(u1.z), Cc2), 0.f), a2);
      a3 = fmaf(w1, fmaxf(fmaf(Aa3, bf2f(u1.w), Cc3), 0.f), a3);
      a0 = fmaf(w2, fmaxf(fmaf(Aa0, bf2f(u2.x), Cc0), 0.f), a0);
      a1 = fmaf(w2, fmaxf(fmaf(Aa1, bf2f(u2.y), Cc1), 0.f), a1);
      a2 = fmaf(w2, fmaxf(fmaf(Aa2, bf2f(u2.z), Cc2), 0.f), a2);
      a3 = fmaf(w2, fmaxf(fmaf(Aa3, bf2f(u2.w), Cc3), 0.f), a3);
      a0 = fmaf(w3, fmaxf(fmaf(Aa0, bf2f(u3.x), Cc0), 0.f), a0);
      a1 = fmaf(w3, fmaxf(fmaf(Aa1, bf2f(u3.y), Cc1), 0.f), a1);
      a2 = fmaf(w3, fmaxf(fmaf(Aa2, bf2f(u3.z), Cc2), 0.f), a2);
      a3 = fmaf(w3, fmaxf(fmaf(Aa3, bf2f(u3.w), Cc3), 0.f), a3);
    }
    for (; p < p1; ++p) {
      int4 e0 = sedge[p];
      ushort4 u0 = *(const ushort4*)&h2b[(size_t)e0.x * HID + l * 4];
      float w0 = __int_as_float(e0.z);
      a0 = fmaf(w0, fmaxf(fmaf(Aa0, bf2f(u0.x), Cc0), 0.f), a0);
      a1 = fmaf(w0, fmaxf(fmaf(Aa1, bf2f(u0.y), Cc1), 0.f), a1);
      a2 = fmaf(w0, fmaxf(fmaf(Aa2, bf2f(u0.z), Cc2), 0.f), a2);
      a3 = fmaf(w0, fmaxf(fmaf(Aa3, bf2f(u0.w), Cc3), 0.f), a3);
    }
    a0 *= invd; a1 *= invd; a2 *= invd; a3 *= invd;
    float4 st = {a0, a1, a2, a3};
    *(float4*)&out[(size_t)node * HID + l * 4] = st;
    ps0 += a0; ps1 += a1; ps2 += a2; ps3 += a3;
    q0 += a0 * a0; q1 += a1 * a1; q2 += a2 * a2; q3 += a3 * a3;
  }
  red[0][g][l][0] = ps0; red[0][g][l][1] = ps1; red[0][g][l][2] = ps2; red[0][g][l][3] = ps3;
  red[1][g][l][0] = q0;  red[1][g][l][1] = q1;  red[1][g][l][2] = q2;  red[1][g][l][3] = q3;
  __syncthreads();
  if (g == 0) {
#pragma unroll
    for (int j = 0; j < 4; ++j) {
      float s = 0, s2 = 0;
#pragma unroll
      for (int gg = 0; gg < 8; ++gg) { s += red[0][gg][l][j]; s2 += red[1][gg][l][j]; }
      atomicAdd(&gsum[l * 4 + j], s);
      atomicAdd(&gsq[l * 4 + j], s2);
    }
  }
}

// ---------------- final in-place affine on d_out ----------------
__global__ void k_final(float* __restrict__ out, const float* __restrict__ A,
                        const float* __restrict__ C, int n) {
  __shared__ float la[HID], lc[HID];
  if (threadIdx.x < HID) { la[threadIdx.x] = A[threadIdx.x]; lc[threadIdx.x] = C[threadIdx.x]; }
  __syncthreads();
  int total = n * 32;  // float4 count
  for (int i = blockIdx.x * blockDim.x + threadIdx.x; i < total; i += gridDim.x * blockDim.x) {
    float4 v = *(float4*)(out + (size_t)i * 4);
    int cg = (i & 31) * 4;
    v.x = fmaf(la[cg + 0], v.x, lc[cg + 0]);
    v.y = fmaf(la[cg + 1], v.y, lc[cg + 1]);
    v.z = fmaf(la[cg + 2], v.z, lc[cg + 2]);
    v.w = fmaf(la[cg + 3], v.w, lc[cg + 3]);
    *(float4*)(out + (size_t)i * 4) = v;
  }
}

extern "C" void kernel_launch(void* const* d_in, const int* in_sizes, int n_in,
                              void* d_out, int out_size, void* d_ws, size_t ws_size,
                              hipStream_t stream) {
  const int* x = (const int*)d_in[0];
  const int* ei = (const int*)d_in[1];
  const float* ew = (const float*)d_in[2];
  const float* emb = (const float*)d_in[3];
  const float* gw = (const float*)d_in[4];
  const float* gb = (const float*)d_in[5];
  const float* gms = (const float*)d_in[6];
  float* out = (float*)d_out;

  const int n = in_sizes[0];        // 100000
  const int e = in_sizes[1] / 2;    // 1600000
  const int* row = ei;
  const int* col = ei + e;

  // workspace layout, in 4-byte units, 128B-aligned chunks
  float* wsf = (float*)d_ws;
  size_t o = 0;
  auto alloc = [&](size_t elems) -> size_t { size_t r = o; o += ((elems + 31) & ~(size_t)31); return r; };
  size_t deg_o = alloc(n);
  size_t cnt_o = alloc(n + 1);
  size_t hist_o = alloc(65);
  size_t sum2_o = alloc(HID), sq2_o = alloc(HID), sum4_o = alloc(HID), sq4_o = alloc(HID);
  size_t zero_end = o;                       // everything above must be zeroed
  size_t A12_o = alloc(HID), C12_o = alloc(HID), A34_o = alloc(HID), C34_o = alloc(HID);
  size_t rowptr_o = alloc(n + 1);
  size_t cursor_o = alloc(n + 1);
  size_t bsum_o = alloc(64);
  size_t emb1_o = alloc(65 * HID);
  size_t sedge_o = alloc((size_t)e * 4);     // int4 per edge
  size_t h2b_o = alloc((size_t)n * HID / 2); // bf16 (ushort) per element

  float* deg = wsf + deg_o;
  int* cnt = (int*)(wsf + cnt_o);
  int* hist = (int*)(wsf + hist_o);
  float* sum2 = wsf + sum2_o; float* sq2 = wsf + sq2_o;
  float* sum4 = wsf + sum4_o; float* sq4 = wsf + sq4_o;
  float* A12 = wsf + A12_o; float* C12 = wsf + C12_o;
  float* A34 = wsf + A34_o; float* C34 = wsf + C34_o;
  int* rowptr = (int*)(wsf + rowptr_o);
  int* cursor = (int*)(wsf + cursor_o);
  int* bsum = (int*)(wsf + bsum_o);
  float* emb1 = wsf + emb1_o;
  int4* sedge = (int4*)(wsf + sedge_o);
  unsigned short* h2b = (unsigned short*)(wsf + h2b_o);

  const float invN = 1.0f / (float)n;

  hipMemsetAsync(d_ws, 0, zero_end * sizeof(float), stream);
  k_hist<<<256, 256, 0, stream>>>(x, n, hist);
  k_degcnt<<<2048, 256, 0, stream>>>(row, ew, e, deg, cnt);
  int nb = (n + 1 + 2047) / 2048;
  k_scan_partial<<<nb, 256, 0, stream>>>(cnt, n + 1, bsum);
  k_scan_bsum<<<1, 64, 0, stream>>>(bsum, nb);
  k_scan_final<<<nb, 256, 0, stream>>>(cnt, n + 1, bsum, rowptr, cursor);
  k_scatter<<<2048, 256, 0, stream>>>(row, col, ew, x, e, cursor, sedge);
  k_gn0<<<1, HID, 0, stream>>>(emb, hist, gw, gb, gms, invN, emb1);
  k_spmm1<<<2048, 256, 0, stream>>>(rowptr, sedge, emb1, deg, n, h2b, sum2, sq2);
  k_gnchain<<<1, HID, 0, stream>>>(sum2, sq2, invN, gw, gb, gms, 1, 2, A12, C12);
  k_spmm2<<<2048, 256, 0, stream>>>(rowptr, sedge, h2b, deg, A12, C12, n, out, sum4, sq4);
  k_gnchain<<<1, HID, 0, stream>>>(sum4, sq4, invN, gw, gb, gms, 3, 4, A34, C34);
  k_final<<<2048, 256, 0, stream>>>(out, A34, C34, n);
}

// Round 5
// 567.875 us; speedup vs baseline: 1.6010x; 1.4813x over previous
//
#include <hip/hip_runtime.h>

#define HID 128
#define EPSF 1e-6f

__device__ inline unsigned f2bf(float f) {
  unsigned u = __float_as_uint(f);
  return (u + 0x7fffu + ((u >> 16) & 1u)) >> 16;  // RNE
}

// ---------------- histogram of x (65 bins) ----------------
__global__ void k_hist(const int* __restrict__ x, int n, int* __restrict__ hist) {
  __shared__ int lh[65];
  int t = threadIdx.x;
  if (t < 65) lh[t] = 0;
  __syncthreads();
  for (int i = blockIdx.x * blockDim.x + t; i < n; i += gridDim.x * blockDim.x)
    atomicAdd(&lh[x[i]], 1);
  __syncthreads();
  if (t < 65 && lh[t]) atomicAdd(&hist[t], lh[t]);
}

// ---------------- per-row edge count (int only; weighted deg now fused into spmm) ----
__global__ void k_cnt(const int* __restrict__ row, int e, int* __restrict__ cnt) {
  for (int i = blockIdx.x * blockDim.x + threadIdx.x; i < e; i += gridDim.x * blockDim.x)
    atomicAdd(&cnt[row[i]], 1);
}

// ---------------- 3-phase exclusive scan over cnt[0..n) -> rowptr ----------------
__global__ void k_scan_partial(const int* __restrict__ cnt, int n, int* __restrict__ bsum) {
  __shared__ int sh[256];
  int t = threadIdx.x;
  int base = blockIdx.x * 2048 + t * 8;
  int s = 0;
#pragma unroll
  for (int j = 0; j < 8; ++j) { int idx = base + j; if (idx < n) s += cnt[idx]; }
  sh[t] = s; __syncthreads();
  for (int off = 128; off > 0; off >>= 1) {
    if (t < off) sh[t] += sh[t + off];
    __syncthreads();
  }
  if (t == 0) bsum[blockIdx.x] = sh[0];
}

__global__ void k_scan_bsum(int* __restrict__ bsum, int nb) {
  if (threadIdx.x == 0 && blockIdx.x == 0) {
    int acc = 0;
    for (int i = 0; i < nb; ++i) { int v = bsum[i]; bsum[i] = acc; acc += v; }
  }
}

__global__ void k_scan_final(const int* __restrict__ cnt, int n, const int* __restrict__ bsum,
                             int* __restrict__ rowptr, int* __restrict__ cursor) {
  __shared__ int sh[256];
  int t = threadIdx.x;
  int base = blockIdx.x * 2048 + t * 8;
  int v[8]; int s = 0;
#pragma unroll
  for (int j = 0; j < 8; ++j) { int idx = base + j; v[j] = (idx < n) ? cnt[idx] : 0; s += v[j]; }
  sh[t] = s; __syncthreads();
  for (int off = 1; off < 256; off <<= 1) {
    int val = (t >= off) ? sh[t - off] : 0;
    __syncthreads();
    sh[t] += val;
    __syncthreads();
  }
  int off0 = bsum[blockIdx.x] + sh[t] - s;  // exclusive prefix for this thread
#pragma unroll
  for (int j = 0; j < 8; ++j) {
    int idx = base + j;
    if (idx < n) { rowptr[idx] = off0; cursor[idx] = off0; off0 += v[j]; }
  }
}

// ---------------- scatter edges into CSR order: ({col | x<<17}, ew) ----------------
__global__ void k_scatter(const int* __restrict__ row, const int* __restrict__ col,
                          const float* __restrict__ ew, const int* __restrict__ x, int e,
                          int* __restrict__ cursor, int2* __restrict__ sedge) {
  for (int i = blockIdx.x * blockDim.x + threadIdx.x; i < e; i += gridDim.x * blockDim.x) {
    int r = row[i];
    int c = col[i];
    int xc = x[c];
    int pos = atomicAdd(&cursor[r], 1);
    sedge[pos] = make_int2(c | (xc << 17), __float_as_int(ew[i]));
  }
}

// ---------------- fold GN0 into the embedding table ----------------
__global__ void k_gn0(const float* __restrict__ emb, const int* __restrict__ hist,
                      const float* __restrict__ gw, const float* __restrict__ gb,
                      const float* __restrict__ gms, float invN,
                      float* __restrict__ emb1) {
  int d = threadIdx.x;  // 128 threads
  float s = 0.f, s2 = 0.f;
  for (int k = 0; k < 65; ++k) {
    float v = emb[k * HID + d];
    float c = (float)hist[k];
    s += c * v; s2 += c * v * v;
  }
  float m = s * invN, E2 = s2 * invN;
  float ms0 = gms[d], w0 = gw[d], b0 = gb[d];
  float sh = m * ms0;
  float a = w0 / sqrtf(E2 - 2.f * sh * m + sh * sh + EPSF);
  float c = b0 - a * sh;
  for (int k = 0; k < 65; ++k) emb1[k * HID + d] = fmaf(a, emb[k * HID + d], c);
}

// ---------------- chained double-GraphNorm -> per-column affine ----------------
__global__ void k_gnchain(const float* __restrict__ gsum, const float* __restrict__ gsq,
                          float invN, const float* __restrict__ gw, const float* __restrict__ gb,
                          const float* __restrict__ gms, int i1, int i2,
                          float* __restrict__ A, float* __restrict__ C) {
  int d = threadIdx.x;  // 128 threads
  float m = gsum[d] * invN, E2 = gsq[d] * invN;
  float ms1 = gms[i1 * HID + d], w1 = gw[i1 * HID + d], b1 = gb[i1 * HID + d];
  float sh1 = m * ms1;
  float a1 = w1 / sqrtf(E2 - 2.f * sh1 * m + sh1 * sh1 + EPSF);
  float c1 = b1 - a1 * sh1;
  float m2 = a1 * m + c1;
  float E2b = a1 * a1 * E2 + 2.f * a1 * c1 * m + c1 * c1;
  float ms2 = gms[i2 * HID + d], w2 = gw[i2 * HID + d], b2 = gb[i2 * HID + d];
  float sh2 = m2 * ms2;
  float a2 = w2 / sqrtf(E2b - 2.f * sh2 * m2 + sh2 * sh2 + EPSF);
  float c2 = b2 - a2 * sh2;
  A[d] = a2 * a1;
  C[d] = a2 * c1 + c2;
}

// ---------------- SpMM1: wave-per-node, LDS-resident emb1, Sigma(w) fused ----------
__global__ __launch_bounds__(256) void k_spmm1(
    const int* __restrict__ rowptr, const int2* __restrict__ sedge,
    const float* __restrict__ emb1, int n, int nwaves,
    unsigned* __restrict__ h2b, float* __restrict__ gsum, float* __restrict__ gsq) {
  __shared__ float lemb[65 * HID];
  __shared__ float red[2][4][64][2];
  int t = threadIdx.x;
  for (int i = t; i < 65 * HID; i += 256) lemb[i] = emb1[i];
  __syncthreads();
  int l = t & 63, wv = t >> 6;
  int gwid = blockIdx.x * 4 + wv;
  float ps0 = 0, ps1 = 0, q0 = 0, q1 = 0;
  for (int node = gwid; node < n; node += nwaves) {
    int nd = __builtin_amdgcn_readfirstlane(node);
    int p0 = rowptr[nd], p1 = rowptr[nd + 1];
    float wsum = 0.f, a0 = 0.f, a1 = 0.f;
    int p = p0;
    int nfull = p0 + ((p1 - p0) & ~7);
    for (; p < nfull; p += 8) {
      int2 b[8];
#pragma unroll
      for (int k = 0; k < 8; ++k) b[k] = sedge[p + k];
#pragma unroll
      for (int k = 0; k < 8; ++k) {
        int xc = b[k].x >> 17;
        float w = __int_as_float(b[k].y);
        const float2 v = *(const float2*)&lemb[xc * HID + l * 2];
        wsum += w;
        a0 = fmaf(w, v.x, a0);
        a1 = fmaf(w, v.y, a1);
      }
    }
    for (; p < p1; ++p) {
      int2 b = sedge[p];
      int xc = b.x >> 17;
      float w = __int_as_float(b.y);
      const float2 v = *(const float2*)&lemb[xc * HID + l * 2];
      wsum += w;
      a0 = fmaf(w, v.x, a0);
      a1 = fmaf(w, v.y, a1);
    }
    float d = (wsum < 0.5f) ? wsum + 1.0f : wsum;
    float invd = 1.0f / d;
    a0 *= invd; a1 *= invd;
    h2b[(size_t)node * (HID / 2) + l] = f2bf(a0) | (f2bf(a1) << 16);
    ps0 += a0; ps1 += a1; q0 += a0 * a0; q1 += a1 * a1;
  }
  red[0][wv][l][0] = ps0; red[0][wv][l][1] = ps1;
  red[1][wv][l][0] = q0;  red[1][wv][l][1] = q1;
  __syncthreads();
  if (wv == 0) {
    float s0 = 0, s1 = 0, t0 = 0, t1 = 0;
#pragma unroll
    for (int k = 0; k < 4; ++k) {
      s0 += red[0][k][l][0]; s1 += red[0][k][l][1];
      t0 += red[1][k][l][0]; t1 += red[1][k][l][1];
    }
    atomicAdd(&gsum[l * 2], s0); atomicAdd(&gsum[l * 2 + 1], s1);
    atomicAdd(&gsq[l * 2], t0);  atomicAdd(&gsq[l * 2 + 1], t1);
  }
}

// ---------------- SpMM2: wave-per-node, 8-deep pipelined bf16 gathers ----------------
__global__ __launch_bounds__(256) void k_spmm2(
    const int* __restrict__ rowptr, const int2* __restrict__ sedge,
    const unsigned* __restrict__ h2b,
    const float* __restrict__ A, const float* __restrict__ C,
    int n, int nwaves, float* __restrict__ out,
    float* __restrict__ gsum, float* __restrict__ gsq) {
  __shared__ float red[2][4][64][2];
  int t = threadIdx.x;
  int l = t & 63, wv = t >> 6;
  int gwid = blockIdx.x * 4 + wv;
  float A0 = A[l * 2], A1 = A[l * 2 + 1], C0 = C[l * 2], C1 = C[l * 2 + 1];
  float ps0 = 0, ps1 = 0, q0 = 0, q1 = 0;
  for (int node = gwid; node < n; node += nwaves) {
    int nd = __builtin_amdgcn_readfirstlane(node);
    int p0 = rowptr[nd], p1 = rowptr[nd + 1];
    float wsum = 0.f, a0 = 0.f, a1 = 0.f;
    int cntf = (p1 - p0) >> 3;  // full batches of 8
    int p = p0;
    int2 b[8], nb[8];
    if (cntf) {
#pragma unroll
      for (int k = 0; k < 8; ++k) b[k] = sedge[p + k];
    }
    for (int it = 0; it < cntf; ++it) {
      unsigned u[8];
#pragma unroll
      for (int k = 0; k < 8; ++k) {
        int c = b[k].x & 0x1FFFF;
        u[k] = h2b[(size_t)c * (HID / 2) + l];
      }
      p += 8;
      if (it + 1 < cntf) {
#pragma unroll
        for (int k = 0; k < 8; ++k) nb[k] = sedge[p + k];
      }
#pragma unroll
      for (int k = 0; k < 8; ++k) {
        float w = __int_as_float(b[k].y);
        wsum += w;
        float h0 = __uint_as_float(u[k] << 16);
        float h1 = __uint_as_float(u[k] & 0xFFFF0000u);
        a0 = fmaf(w, fmaxf(fmaf(A0, h0, C0), 0.f), a0);
        a1 = fmaf(w, fmaxf(fmaf(A1, h1, C1), 0.f), a1);
      }
#pragma unroll
      for (int k = 0; k < 8; ++k) b[k] = nb[k];
    }
    for (; p < p1; ++p) {
      int2 e = sedge[p];
      int c = e.x & 0x1FFFF;
      unsigned uu = h2b[(size_t)c * (HID / 2) + l];
      float w = __int_as_float(e.y);
      wsum += w;
      float h0 = __uint_as_float(uu << 16);
      float h1 = __uint_as_float(uu & 0xFFFF0000u);
      a0 = fmaf(w, fmaxf(fmaf(A0, h0, C0), 0.f), a0);
      a1 = fmaf(w, fmaxf(fmaf(A1, h1, C1), 0.f), a1);
    }
    float d = (wsum < 0.5f) ? wsum + 1.0f : wsum;
    float invd = 1.0f / d;
    a0 *= invd; a1 *= invd;
    *(float2*)&out[(size_t)node * HID + l * 2] = make_float2(a0, a1);
    ps0 += a0; ps1 += a1; q0 += a0 * a0; q1 += a1 * a1;
  }
  red[0][wv][l][0] = ps0; red[0][wv][l][1] = ps1;
  red[1][wv][l][0] = q0;  red[1][wv][l][1] = q1;
  __syncthreads();
  if (wv == 0) {
    float s0 = 0, s1 = 0, t0 = 0, t1 = 0;
#pragma unroll
    for (int k = 0; k < 4; ++k) {
      s0 += red[0][k][l][0]; s1 += red[0][k][l][1];
      t0 += red[1][k][l][0]; t1 += red[1][k][l][1];
    }
    atomicAdd(&gsum[l * 2], s0); atomicAdd(&gsum[l * 2 + 1], s1);
    atomicAdd(&gsq[l * 2], t0);  atomicAdd(&gsq[l * 2 + 1], t1);
  }
}

// ---------------- final in-place affine on d_out ----------------
__global__ void k_final(float* __restrict__ out, const float* __restrict__ A,
                        const float* __restrict__ C, int n) {
  __shared__ float la[HID], lc[HID];
  if (threadIdx.x < HID) { la[threadIdx.x] = A[threadIdx.x]; lc[threadIdx.x] = C[threadIdx.x]; }
  __syncthreads();
  int total = n * 32;  // float4 count
  for (int i = blockIdx.x * blockDim.x + threadIdx.x; i < total; i += gridDim.x * blockDim.x) {
    float4 v = *(float4*)(out + (size_t)i * 4);
    int cg = (i & 31) * 4;
    v.x = fmaf(la[cg + 0], v.x, lc[cg + 0]);
    v.y = fmaf(la[cg + 1], v.y, lc[cg + 1]);
    v.z = fmaf(la[cg + 2], v.z, lc[cg + 2]);
    v.w = fmaf(la[cg + 3], v.w, lc[cg + 3]);
    *(float4*)(out + (size_t)i * 4) = v;
  }
}

extern "C" void kernel_launch(void* const* d_in, const int* in_sizes, int n_in,
                              void* d_out, int out_size, void* d_ws, size_t ws_size,
                              hipStream_t stream) {
  const int* x = (const int*)d_in[0];
  const int* ei = (const int*)d_in[1];
  const float* ew = (const float*)d_in[2];
  const float* emb = (const float*)d_in[3];
  const float* gw = (const float*)d_in[4];
  const float* gb = (const float*)d_in[5];
  const float* gms = (const float*)d_in[6];
  float* out = (float*)d_out;

  const int n = in_sizes[0];        // 100000
  const int e = in_sizes[1] / 2;    // 1600000
  const int* row = ei;
  const int* col = ei + e;

  // workspace layout, in 4-byte units, 128B-aligned chunks
  float* wsf = (float*)d_ws;
  size_t o = 0;
  auto alloc = [&](size_t elems) -> size_t { size_t r = o; o += ((elems + 31) & ~(size_t)31); return r; };
  size_t cnt_o = alloc(n + 1);
  size_t hist_o = alloc(65);
  size_t sum2_o = alloc(HID), sq2_o = alloc(HID), sum4_o = alloc(HID), sq4_o = alloc(HID);
  size_t zero_end = o;                       // everything above must be zeroed
  size_t A12_o = alloc(HID), C12_o = alloc(HID), A34_o = alloc(HID), C34_o = alloc(HID);
  size_t rowptr_o = alloc(n + 1);
  size_t cursor_o = alloc(n + 1);
  size_t bsum_o = alloc(64);
  size_t emb1_o = alloc(65 * HID);
  size_t sedge_o = alloc((size_t)e * 2);     // int2 per edge
  size_t h2b_o = alloc((size_t)n * HID / 2); // bf16 pairs (uint) per 2 elements

  int* cnt = (int*)(wsf + cnt_o);
  int* hist = (int*)(wsf + hist_o);
  float* sum2 = wsf + sum2_o; float* sq2 = wsf + sq2_o;
  float* sum4 = wsf + sum4_o; float* sq4 = wsf + sq4_o;
  float* A12 = wsf + A12_o; float* C12 = wsf + C12_o;
  float* A34 = wsf + A34_o; float* C34 = wsf + C34_o;
  int* rowptr = (int*)(wsf + rowptr_o);
  int* cursor = (int*)(wsf + cursor_o);
  int* bsum = (int*)(wsf + bsum_o);
  float* emb1 = wsf + emb1_o;
  int2* sedge = (int2*)(wsf + sedge_o);
  unsigned* h2b = (unsigned*)(wsf + h2b_o);

  const float invN = 1.0f / (float)n;
  const int nblk = 2048;
  const int nwaves = nblk * 4;

  hipMemsetAsync(d_ws, 0, zero_end * sizeof(float), stream);
  k_hist<<<256, 256, 0, stream>>>(x, n, hist);
  k_cnt<<<2048, 256, 0, stream>>>(row, e, cnt);
  int nb = (n + 1 + 2047) / 2048;
  k_scan_partial<<<nb, 256, 0, stream>>>(cnt, n + 1, bsum);
  k_scan_bsum<<<1, 64, 0, stream>>>(bsum, nb);
  k_scan_final<<<nb, 256, 0, stream>>>(cnt, n + 1, bsum, rowptr, cursor);
  k_scatter<<<2048, 256, 0, stream>>>(row, col, ew, x, e, cursor, sedge);
  k_gn0<<<1, HID, 0, stream>>>(emb, hist, gw, gb, gms, invN, emb1);
  k_spmm1<<<nblk, 256, 0, stream>>>(rowptr, sedge, emb1, n, nwaves, h2b, sum2, sq2);
  k_gnchain<<<1, HID, 0, stream>>>(sum2, sq2, invN, gw, gb, gms, 1, 2, A12, C12);
  k_spmm2<<<nblk, 256, 0, stream>>>(rowptr, sedge, h2b, A12, C12, n, nwaves, out, sum4, sq4);
  k_gnchain<<<1, HID, 0, stream>>>(sum4, sq4, invN, gw, gb, gms, 3, 4, A34, C34);
  k_final<<<2048, 256, 0, stream>>>(out, A34, C34, n);
}